// Round 2
// baseline (541.371 us; speedup 1.0000x reference)
//
#include <hip/hip_runtime.h>
#include <hip/hip_cooperative_groups.h>

namespace cg = cooperative_groups;

// ---------------------------------------------------------------------------
// color_invariant_quadruplet: 3-hop label gather + 6-way equality embedding sum
//
// The 6 equality bits take 64 combinations; each maps to a fixed 64-float row.
// Single cooperative kernel, 5 phases, 3 grid syncs:
//   P0 : build 64x64 table (16 KB) with reference add order (bit-exact)
//   P1 : per g-edge packed endpoint labels   (4 edges/thread, int4 idx loads)
//   P2 : per h-edge packed (z_ss, z_dd)      (4 edges/thread)
//   P3 : per i-edge 6-bit combo byte         (4 edges/thread, uint store)
//   P4 : pure streaming table-row write      (write-BW-bound, 512 MB)
//
// Round 2 change: fuse the 5 kernels (kill 4 launch gaps + ramp/drains) and
// give the latency-bound gather phases 4x MLP (8 independent random gathers
// in flight per thread, packed stores).
// ---------------------------------------------------------------------------

#define N_FEAT 64

__device__ __forceinline__ unsigned combo6(unsigned p, unsigned q) {
    // p = (za | zc<<8), q = (zb | zd<<8)
    unsigned za = p & 0xffu, zc = p >> 8;
    unsigned zb = q & 0xffu, zd = q >> 8;
    return (unsigned)(za == zc)
         | ((unsigned)(za == zb) << 1)
         | ((unsigned)(zc == zb) << 2)
         | ((unsigned)(za == zd) << 3)
         | ((unsigned)(zc == zd) << 4)
         | ((unsigned)(zb == zd) << 5);
}

__global__ __launch_bounds__(256, 4)
void fused_kernel(const int* __restrict__ z,
                  const int* __restrict__ src_g,
                  const int* __restrict__ dst_g,
                  const int* __restrict__ src_h,
                  const int* __restrict__ dst_h,
                  const int* __restrict__ src_i,
                  const int* __restrict__ dst_i,
                  const float* __restrict__ e1,
                  const float* __restrict__ e2,
                  const float* __restrict__ e3,
                  const float* __restrict__ e4,
                  const float* __restrict__ e5,
                  const float* __restrict__ e6,
                  float* __restrict__ table,
                  unsigned short* __restrict__ zg,   // packed (z_src | z_dst<<8)
                  unsigned short* __restrict__ zh,   // packed (z_ss | z_dd<<8)
                  unsigned char* __restrict__ combo,
                  float* __restrict__ out,
                  int E_G, int E_H, int E_I) {
    cg::grid_group grid = cg::this_grid();
    const int tid = blockIdx.x * blockDim.x + threadIdx.x;
    const int nth = gridDim.x * blockDim.x;

    // ---- P0: 64x64 table, reference left-to-right add order (bit-exact) ----
    for (int idx = tid; idx < 64 * N_FEAT; idx += nth) {
        int cmb = idx >> 6;
        int f   = idx & (N_FEAT - 1);
        float v = e1[((cmb >> 0) & 1) * N_FEAT + f];
        v      += e2[((cmb >> 1) & 1) * N_FEAT + f];
        v      += e3[((cmb >> 2) & 1) * N_FEAT + f];
        v      += e4[((cmb >> 3) & 1) * N_FEAT + f];
        v      += e5[((cmb >> 4) & 1) * N_FEAT + f];
        v      += e6[((cmb >> 5) & 1) * N_FEAT + f];
        table[idx] = v;
    }

    // ---- P1: hop1, 4 g-edges per thread ----
    const int ng4 = E_G >> 2;
    for (int i = tid; i < ng4; i += nth) {
        int4 s = ((const int4*)src_g)[i];
        int4 d = ((const int4*)dst_g)[i];
        unsigned r0 = ((unsigned)z[s.x] & 0xffu)
                    | (((unsigned)z[d.x] & 0xffu) << 8)
                    | (((unsigned)z[s.y] & 0xffu) << 16)
                    | (((unsigned)z[d.y] & 0xffu) << 24);
        unsigned r1 = ((unsigned)z[s.z] & 0xffu)
                    | (((unsigned)z[d.z] & 0xffu) << 8)
                    | (((unsigned)z[s.w] & 0xffu) << 16)
                    | (((unsigned)z[d.w] & 0xffu) << 24);
        ((uint2*)zg)[i] = make_uint2(r0, r1);
    }
    for (int e = (ng4 << 2) + tid; e < E_G; e += nth) {
        zg[e] = (unsigned short)(((unsigned)z[src_g[e]] & 0xffu)
                               | (((unsigned)z[dst_g[e]] & 0xffu) << 8));
    }
    grid.sync();

    // ---- P2: hop2, 4 h-edges per thread ----
    const int nh4 = E_H >> 2;
    for (int i = tid; i < nh4; i += nth) {
        int4 s = ((const int4*)src_h)[i];
        int4 d = ((const int4*)dst_h)[i];
        unsigned a0 = zg[s.x], b0 = zg[d.x];
        unsigned a1 = zg[s.y], b1 = zg[d.y];
        unsigned a2 = zg[s.z], b2 = zg[d.z];
        unsigned a3 = zg[s.w], b3 = zg[d.w];
        // zh = z_src[src_h] (low byte of a) | z_dst[dst_h] (high byte of b)
        unsigned r0 = (a0 & 0xffu) | (b0 & 0xff00u)
                    | ((a1 & 0xffu) << 16) | ((b1 & 0xff00u) << 16);
        unsigned r1 = (a2 & 0xffu) | (b2 & 0xff00u)
                    | ((a3 & 0xffu) << 16) | ((b3 & 0xff00u) << 16);
        ((uint2*)zh)[i] = make_uint2(r0, r1);
    }
    for (int e = (nh4 << 2) + tid; e < E_H; e += nth) {
        unsigned a = zg[src_h[e]], b = zg[dst_h[e]];
        zh[e] = (unsigned short)((a & 0xffu) | (b & 0xff00u));
    }
    grid.sync();

    // ---- P3: combo, 4 i-edges per thread ----
    const int ni4 = E_I >> 2;
    for (int i = tid; i < ni4; i += nth) {
        int4 s = ((const int4*)src_i)[i];
        int4 d = ((const int4*)dst_i)[i];
        unsigned c0 = combo6(zh[s.x], zh[d.x]);
        unsigned c1 = combo6(zh[s.y], zh[d.y]);
        unsigned c2 = combo6(zh[s.z], zh[d.z]);
        unsigned c3 = combo6(zh[s.w], zh[d.w]);
        ((unsigned*)combo)[i] = c0 | (c1 << 8) | (c2 << 16) | (c3 << 24);
    }
    for (int e = (ni4 << 2) + tid; e < E_I; e += nth) {
        combo[e] = (unsigned char)combo6(zh[src_i[e]], zh[dst_i[e]]);
    }
    grid.sync();

    // ---- P4: streaming write. 16 threads per edge, 1 float4 each;
    //      consecutive lanes -> consecutive float4s (1 KB/wave coalesced). ----
    const long long total = (long long)E_I * 16;
    for (long long t = tid; t < total; t += nth) {
        int e  = (int)(t >> 4);
        int c  = (int)(t & 15);
        int cb = combo[e];
        float4 v = ((const float4*)(table + cb * N_FEAT))[c];
        ((float4*)(out + (size_t)e * N_FEAT))[c] = v;
    }
}

extern "C" void kernel_launch(void* const* d_in, const int* in_sizes, int n_in,
                              void* d_out, int out_size, void* d_ws, size_t ws_size,
                              hipStream_t stream) {
    // setup_inputs order: z, src_g, dst_g, src_h, dst_h, src_i, dst_i, e1..e6
    const int* z     = (const int*)d_in[0];
    const int* src_g = (const int*)d_in[1];
    const int* dst_g = (const int*)d_in[2];
    const int* src_h = (const int*)d_in[3];
    const int* dst_h = (const int*)d_in[4];
    const int* src_i = (const int*)d_in[5];
    const int* dst_i = (const int*)d_in[6];
    const float* e1  = (const float*)d_in[7];
    const float* e2  = (const float*)d_in[8];
    const float* e3  = (const float*)d_in[9];
    const float* e4  = (const float*)d_in[10];
    const float* e5  = (const float*)d_in[11];
    const float* e6  = (const float*)d_in[12];

    int E_G = in_sizes[1];
    int E_H = in_sizes[3];
    int E_I = in_sizes[5];

    // Workspace layout (256B-aligned):
    //   [0, 16384)   : float table[64][64]
    //   [+2*E_G]     : ushort zg[E_G]
    //   [+2*E_H]     : ushort zh[E_H]
    //   [+E_I]       : uchar combo[E_I]
    char* ws = (char*)d_ws;
    float* table = (float*)ws;
    size_t off   = 64 * N_FEAT * sizeof(float);               // 16384
    unsigned short* zg = (unsigned short*)(ws + off);
    off += (size_t)E_G * sizeof(unsigned short);
    off  = (off + 255) & ~(size_t)255;
    unsigned short* zh = (unsigned short*)(ws + off);
    off += (size_t)E_H * sizeof(unsigned short);
    off  = (off + 255) & ~(size_t)255;
    unsigned char* combo = (unsigned char*)(ws + off);

    float* out = (float*)d_out;

    void* args[] = {
        (void*)&z, (void*)&src_g, (void*)&dst_g,
        (void*)&src_h, (void*)&dst_h, (void*)&src_i, (void*)&dst_i,
        (void*)&e1, (void*)&e2, (void*)&e3, (void*)&e4, (void*)&e5, (void*)&e6,
        (void*)&table, (void*)&zg, (void*)&zh, (void*)&combo, (void*)&out,
        (void*)&E_G, (void*)&E_H, (void*)&E_I
    };

    // 1024 blocks x 256 threads; __launch_bounds__(256,4) guarantees
    // 4 blocks/CU co-resident on 256 CUs -> cooperative launch is valid.
    hipLaunchCooperativeKernel((const void*)fused_kernel,
                               dim3(1024), dim3(256), args, 0, stream);
}

// Round 3
// 148.825 us; speedup vs baseline: 3.6376x; 3.6376x over previous
//
#include <hip/hip_runtime.h>

// ---------------------------------------------------------------------------
// color_invariant_quadruplet: 3-hop label gather + 6-way equality embedding sum
//
// The 6 equality bits take 64 combinations; each maps to a fixed 64-float row.
// Pipeline (5 one-shot kernels -- NO long grid-stride loops: round 2 showed a
// dependent load->store chain in a grid-stride loop on a small co-resident
// grid serializes each wave to ~1 outstanding store -> 1 TB/s):
//   K0 : build 64x64 table (16 KB), reference add order (bit-exact)
//   K1 : per g-edge packed endpoint labels   (4 edges/thread, int4 idx loads)
//   K2 : per h-edge packed (z_ss, z_dd)      (4 edges/thread)
//   K3a: per i-edge 6-bit combo byte         (4 edges/thread, uint store)
//   K3b: streaming write, 64 edges/block, table in LDS, 4x coalesced 1KB
//        wave-stores per wave, 4 independent stores in flight per thread
// ---------------------------------------------------------------------------

#define N_FEAT 64

// K0: table[combo][f] = e1[b0][f] + ... + e6[b5][f], left-to-right f32 order.
__global__ void build_table_kernel(const float* __restrict__ e1,
                                   const float* __restrict__ e2,
                                   const float* __restrict__ e3,
                                   const float* __restrict__ e4,
                                   const float* __restrict__ e5,
                                   const float* __restrict__ e6,
                                   float* __restrict__ table) {
    int idx = blockIdx.x * blockDim.x + threadIdx.x;   // 0 .. 4095
    if (idx >= 64 * N_FEAT) return;
    int combo = idx >> 6;
    int f     = idx & (N_FEAT - 1);
    float v = e1[((combo >> 0) & 1) * N_FEAT + f];
    v      += e2[((combo >> 1) & 1) * N_FEAT + f];
    v      += e3[((combo >> 2) & 1) * N_FEAT + f];
    v      += e4[((combo >> 3) & 1) * N_FEAT + f];
    v      += e5[((combo >> 4) & 1) * N_FEAT + f];
    v      += e6[((combo >> 5) & 1) * N_FEAT + f];
    table[idx] = v;
}

// K1: hop1, 4 g-edges/thread. 8 independent random z-gathers in flight.
// zg[e] = z_src | z_dst<<8 (z in 0..7 fits a byte).
__global__ void hop1_kernel(const int* __restrict__ z,
                            const int* __restrict__ src_g,
                            const int* __restrict__ dst_g,
                            unsigned short* __restrict__ zg,
                            int n) {
    int i  = blockIdx.x * blockDim.x + threadIdx.x;
    int n4 = n >> 2;
    if (i < n4) {
        int4 s = ((const int4*)src_g)[i];
        int4 d = ((const int4*)dst_g)[i];
        unsigned zs0 = (unsigned)z[s.x], zd0 = (unsigned)z[d.x];
        unsigned zs1 = (unsigned)z[s.y], zd1 = (unsigned)z[d.y];
        unsigned zs2 = (unsigned)z[s.z], zd2 = (unsigned)z[d.z];
        unsigned zs3 = (unsigned)z[s.w], zd3 = (unsigned)z[d.w];
        unsigned r0 = (zs0 & 0xffu) | ((zd0 & 0xffu) << 8)
                    | ((zs1 & 0xffu) << 16) | ((zd1 & 0xffu) << 24);
        unsigned r1 = (zs2 & 0xffu) | ((zd2 & 0xffu) << 8)
                    | ((zs3 & 0xffu) << 16) | ((zd3 & 0xffu) << 24);
        ((uint2*)zg)[i] = make_uint2(r0, r1);
    } else {
        int e = (n4 << 2) + (i - n4);      // tail edges, scalar
        if (e < n) {
            zg[e] = (unsigned short)(((unsigned)z[src_g[e]] & 0xffu)
                                   | (((unsigned)z[dst_g[e]] & 0xffu) << 8));
        }
    }
}

// K2: hop2, 4 h-edges/thread. zh = z_src[src_h] | z_dst[dst_h]<<8.
__global__ void hop2_kernel(const unsigned short* __restrict__ zg,
                            const int* __restrict__ src_h,
                            const int* __restrict__ dst_h,
                            unsigned short* __restrict__ zh,
                            int n) {
    int i  = blockIdx.x * blockDim.x + threadIdx.x;
    int n4 = n >> 2;
    if (i < n4) {
        int4 s = ((const int4*)src_h)[i];
        int4 d = ((const int4*)dst_h)[i];
        unsigned a0 = zg[s.x], b0 = zg[d.x];
        unsigned a1 = zg[s.y], b1 = zg[d.y];
        unsigned a2 = zg[s.z], b2 = zg[d.z];
        unsigned a3 = zg[s.w], b3 = zg[d.w];
        unsigned r0 = (a0 & 0xffu) | (b0 & 0xff00u)
                    | ((a1 & 0xffu) << 16) | ((b1 & 0xff00u) << 16);
        unsigned r1 = (a2 & 0xffu) | (b2 & 0xff00u)
                    | ((a3 & 0xffu) << 16) | ((b3 & 0xff00u) << 16);
        ((uint2*)zh)[i] = make_uint2(r0, r1);
    } else {
        int e = (n4 << 2) + (i - n4);
        if (e < n) {
            unsigned a = zg[src_h[e]], b = zg[dst_h[e]];
            zh[e] = (unsigned short)((a & 0xffu) | (b & 0xff00u));
        }
    }
}

__device__ __forceinline__ unsigned combo6(unsigned p, unsigned q) {
    // p = (za | zc<<8), q = (zb | zd<<8)
    unsigned za = p & 0xffu, zc = p >> 8;
    unsigned zb = q & 0xffu, zd = q >> 8;
    return (unsigned)(za == zc)
         | ((unsigned)(za == zb) << 1)
         | ((unsigned)(zc == zb) << 2)
         | ((unsigned)(za == zd) << 3)
         | ((unsigned)(zc == zd) << 4)
         | ((unsigned)(zb == zd) << 5);
}

// K3a: combo, 4 i-edges/thread, packed uint store.
__global__ void combo_kernel(const unsigned short* __restrict__ zh,
                             const int* __restrict__ src_i,
                             const int* __restrict__ dst_i,
                             unsigned char* __restrict__ combo,
                             int n) {
    int i  = blockIdx.x * blockDim.x + threadIdx.x;
    int n4 = n >> 2;
    if (i < n4) {
        int4 s = ((const int4*)src_i)[i];
        int4 d = ((const int4*)dst_i)[i];
        unsigned p0 = zh[s.x], q0 = zh[d.x];
        unsigned p1 = zh[s.y], q1 = zh[d.y];
        unsigned p2 = zh[s.z], q2 = zh[d.z];
        unsigned p3 = zh[s.w], q3 = zh[d.w];
        unsigned c0 = combo6(p0, q0);
        unsigned c1 = combo6(p1, q1);
        unsigned c2 = combo6(p2, q2);
        unsigned c3 = combo6(p3, q3);
        ((unsigned*)combo)[i] = c0 | (c1 << 8) | (c2 << 16) | (c3 << 24);
    } else {
        int e = (n4 << 2) + (i - n4);
        if (e < n) combo[e] = (unsigned char)combo6(zh[src_i[e]], zh[dst_i[e]]);
    }
}

// K3b: streaming write. 64 edges (16 KB output) per 256-thread block.
// Table staged in LDS (16 KB) -> the only vmem ops per thread are 4
// independent combo-byte loads + 4 stores. Store slot j of wave w covers a
// contiguous 1 KB range (lane-consecutive float4s) -> fully coalesced.
// One-shot: no loop, MLP comes from 4 independent slots/thread + wave count.
__global__ __launch_bounds__(256)
void write_kernel(const unsigned char* __restrict__ combo,
                  const float* __restrict__ table,
                  float* __restrict__ out,
                  int nEdges) {
    __shared__ float4 tbl[64 * 16];           // 64 rows x 16 float4
    int tid = threadIdx.x;
    const float4* t4 = (const float4*)table;
#pragma unroll
    for (int k = 0; k < 4; ++k)
        tbl[k * 256 + tid] = t4[k * 256 + tid];
    __syncthreads();

    long long total = (long long)nEdges * 16;           // total float4s
    long long base  = (long long)blockIdx.x * 1024;     // this block's first f4

    long long f[4];
    int cb[4];
#pragma unroll
    for (int j = 0; j < 4; ++j) {
        f[j]  = base + j * 256 + tid;
        cb[j] = (f[j] < total) ? (int)combo[f[j] >> 4] : 0;
    }
#pragma unroll
    for (int j = 0; j < 4; ++j) {
        if (f[j] < total) {
            int c = (int)(f[j] & 15);
            ((float4*)out)[f[j]] = tbl[cb[j] * 16 + c];
        }
    }
}

extern "C" void kernel_launch(void* const* d_in, const int* in_sizes, int n_in,
                              void* d_out, int out_size, void* d_ws, size_t ws_size,
                              hipStream_t stream) {
    // setup_inputs order: z, src_g, dst_g, src_h, dst_h, src_i, dst_i, e1..e6
    const int* z     = (const int*)d_in[0];
    const int* src_g = (const int*)d_in[1];
    const int* dst_g = (const int*)d_in[2];
    const int* src_h = (const int*)d_in[3];
    const int* dst_h = (const int*)d_in[4];
    const int* src_i = (const int*)d_in[5];
    const int* dst_i = (const int*)d_in[6];
    const float* e1  = (const float*)d_in[7];
    const float* e2  = (const float*)d_in[8];
    const float* e3  = (const float*)d_in[9];
    const float* e4  = (const float*)d_in[10];
    const float* e5  = (const float*)d_in[11];
    const float* e6  = (const float*)d_in[12];

    int E_G = in_sizes[1];
    int E_H = in_sizes[3];
    int E_I = in_sizes[5];

    // Workspace layout (256B-aligned):
    //   [0, 16384)   : float table[64][64]
    //   [+2*E_G]     : ushort zg[E_G]
    //   [+2*E_H]     : ushort zh[E_H]
    //   [+E_I]       : uchar combo[E_I]
    char* ws = (char*)d_ws;
    float* table = (float*)ws;
    size_t off   = 64 * N_FEAT * sizeof(float);               // 16384
    unsigned short* zg = (unsigned short*)(ws + off);
    off += (size_t)E_G * sizeof(unsigned short);
    off  = (off + 255) & ~(size_t)255;
    unsigned short* zh = (unsigned short*)(ws + off);
    off += (size_t)E_H * sizeof(unsigned short);
    off  = (off + 255) & ~(size_t)255;
    unsigned char* combo = (unsigned char*)(ws + off);

    float* out = (float*)d_out;

    // K0
    build_table_kernel<<<16, 256, 0, stream>>>(e1, e2, e3, e4, e5, e6, table);

    // K1: ceil(E_G/4) vector threads + up to 3 tail threads
    {
        int n4 = E_G >> 2, nth = n4 + (E_G - (n4 << 2));
        hop1_kernel<<<(nth + 255) / 256, 256, 0, stream>>>(z, src_g, dst_g, zg, E_G);
    }
    // K2
    {
        int n4 = E_H >> 2, nth = n4 + (E_H - (n4 << 2));
        hop2_kernel<<<(nth + 255) / 256, 256, 0, stream>>>(zg, src_h, dst_h, zh, E_H);
    }
    // K3a
    {
        int n4 = E_I >> 2, nth = n4 + (E_I - (n4 << 2));
        combo_kernel<<<(nth + 255) / 256, 256, 0, stream>>>(zh, src_i, dst_i, combo, E_I);
    }
    // K3b: 64 edges per block
    {
        int blocks = (E_I + 63) / 64;
        write_kernel<<<blocks, 256, 0, stream>>>(combo, table, out, E_I);
    }
}